// Round 1
// 330.842 us; speedup vs baseline: 1.0182x; 1.0182x over previous
//
#include <hip/hip_runtime.h>
#include <hip/hip_bf16.h>
#include <stdint.h>

typedef __attribute__((ext_vector_type(8))) short bf16x8;
typedef __attribute__((ext_vector_type(4))) float f32x4;
typedef __attribute__((ext_vector_type(4))) unsigned short u16x4;

#define B_  4
#define T_  2048
#define D_  1024
#define BM  128
#define BN  128
#define BK  32

__device__ __forceinline__ float bf2f(ushort u) {
  union { unsigned int i; float f; } v; v.i = ((unsigned int)u) << 16; return v.f;
}
__device__ __forceinline__ ushort f2bf(float f) {
  return (ushort)(__bfloat16_as_ushort(__float2bfloat16(f)));
}
__device__ __forceinline__ void async16(const void* g, void* l) {
  __builtin_amdgcn_global_load_lds(
      (const __attribute__((address_space(1))) void*)g,
      (__attribute__((address_space(3))) void*)l, 16, 0, 0);
}
__device__ __forceinline__ int swz4(int r) { return (r ^ (r >> 2)) & 3; }

// ---------------- fused prep: all converts + transposed weight cvts + bias combine ----
__global__ __launch_bounds__(256)
void prep(const float* __restrict__ lat, const float* __restrict__ inp,
          const float* __restrict__ Wl, const float* __restrict__ bl,
          const float* __restrict__ Wu, const float* __restrict__ bu,
          const float* __restrict__ WA, const float* __restrict__ bA,
          const float* __restrict__ WV, const float* __restrict__ bV,
          const float* __restrict__ Wo, const float* __restrict__ bo,
          ushort* __restrict__ xBf, ushort* __restrict__ xBf2,
          ushort* __restrict__ w1, ushort* __restrict__ w2,
          ushort* __restrict__ wCatWo, float* __restrict__ bc, float* __restrict__ bc2)
{
  __shared__ alignas(16) ushort t[64 * 65];
  const long NW = (long)D_ * D_;
  const int bx = blockIdx.x;
  const int tid = threadIdx.x;
  if (bx < 16384) {                     // big tensor cvts
    const float* in = bx < 8192 ? lat : inp;
    ushort* out = bx < 8192 ? xBf : xBf2;
    const long i = (long)(bx & 8191) * 256 + tid;
    const float4 v = *(const float4*)(in + i * 4);
    u16x4 o;
    o[0] = f2bf(v.x); o[1] = f2bf(v.y); o[2] = f2bf(v.z); o[3] = f2bf(v.w);
    *(u16x4*)(out + i * 4) = o;
  } else if (bx < 19456) {              // weight cvts
    const int seg = (bx - 16384) >> 10;
    const float* in  = seg == 0 ? Wu : (seg == 1 ? WV : Wo);
    ushort* out = seg == 0 ? w1 : (seg == 1 ? w1 + NW : wCatWo);
    const long i = (long)((bx - 16384) & 1023) * 256 + tid;
    const float4 v = *(const float4*)(in + i * 4);
    u16x4 o;
    o[0] = f2bf(v.x); o[1] = f2bf(v.y); o[2] = f2bf(v.z); o[3] = f2bf(v.w);
    *(u16x4*)(out + i * 4) = o;
  } else if (bx < 19968) {              // transposed weight cvts
    const int z = (bx - 19456) >> 8;
    const int w = (bx - 19456) & 255;
    const float* in = z ? WA : Wl;
    ushort* out = z ? w2 + NW : w2;
    const int c0 = (w & 15) * 64, r0 = (w >> 4) * 64;
    const int tx = tid & 15, ty = tid >> 4;
#pragma unroll
    for (int i = 0; i < 4; ++i) {
      const int r = ty + i * 16;
      const float4 v = *(const float4*)(in + (long)(r0 + r) * D_ + c0 + tx * 4);
      t[(tx * 4 + 0) * 65 + r] = f2bf(v.x);
      t[(tx * 4 + 1) * 65 + r] = f2bf(v.y);
      t[(tx * 4 + 2) * 65 + r] = f2bf(v.z);
      t[(tx * 4 + 3) * 65 + r] = f2bf(v.w);
    }
    __syncthreads();
#pragma unroll
    for (int i = 0; i < 4; ++i) {
      const int c = ty + i * 16;
      u16x4 v;
#pragma unroll
      for (int j = 0; j < 4; ++j) v[j] = t[c * 65 + tx * 4 + j];
      *(u16x4*)(out + (long)(c0 + c) * D_ + r0 + tx * 4) = v;
    }
  } else {                              // bias combine
    const int z = (bx - 19968) >> 8;
    const int w = (bx - 19968) & 255;
    const float* W    = z ? WV : Wu;
    const float* bin  = z ? bA : bl;
    const float* badd = z ? bV : bu;
    float* out        = z ? bc2 : bc;
    const int wv = tid >> 6, lane = tid & 63;
    const int e = w * 4 + wv;
    const float* row = W + (long)e * D_;
    float s = 0.f;
#pragma unroll
    for (int i = 0; i < 16; ++i) s += row[lane + i * 64] * bin[lane + i * 64];
#pragma unroll
    for (int off = 32; off; off >>= 1) s += __shfl_xor(s, off);
    if (lane == 0) out[e] = s + badd[e];
  }
}

// ---------------- small 128^2 GEMM (kept for the 1024^3 weight-compose) ----------
template<bool OUT_F32, bool HAS_BIAS, bool EXP_OUT>
__global__ __launch_bounds__(256, 2)
void gemm_nt(const ushort* __restrict__ A, const ushort* __restrict__ B,
             const float* __restrict__ bias, void* __restrict__ C,
             int N, int K, long sA, long sB, long sC)
{
  __shared__ alignas(16) ushort As[BM * BK];
  __shared__ alignas(16) ushort Bs[BN * BK];
  const int tid  = threadIdx.x;
  const int wave = tid >> 6;
  const int lane = tid & 63;
  const int wm   = wave >> 1;
  const int wn   = wave & 1;
  const int bz   = blockIdx.z;
  const int tileN = blockIdx.x * BN;
  const int tileM = blockIdx.y * BM;
  A += (long)bz * sA;
  B += (long)bz * sB;

  const int lrow   = lane >> 2;
  const int lchunk = (lane & 3) ^ swz4(lrow);

  f32x4 acc[4][4];
#pragma unroll
  for (int i = 0; i < 4; ++i)
#pragma unroll
    for (int j = 0; j < 4; ++j) acc[i][j] = (f32x4){0.f, 0.f, 0.f, 0.f};

  const int frow = lane & 15;
  const int kg   = lane >> 4;
  const int coff = ((kg ^ swz4(frow)) << 3);

  for (int kt = 0; kt < K; kt += BK) {
    __syncthreads();
#pragma unroll
    for (int i = 0; i < 2; ++i) {
      const int rg  = wave * 2 + i;
      const int row = rg * 16 + lrow;
      async16(A + (long)(tileM + row) * K + kt + lchunk * 8, (void*)(As + rg * 16 * BK));
      async16(B + (long)(tileN + row) * K + kt + lchunk * 8, (void*)(Bs + rg * 16 * BK));
    }
    __syncthreads();
    bf16x8 af[4], bfr[4];
#pragma unroll
    for (int mi = 0; mi < 4; ++mi)
      af[mi] = *(const bf16x8*)(As + (wm * 64 + mi * 16 + frow) * BK + coff);
#pragma unroll
    for (int ni = 0; ni < 4; ++ni)
      bfr[ni] = *(const bf16x8*)(Bs + (wn * 64 + ni * 16 + frow) * BK + coff);
#pragma unroll
    for (int mi = 0; mi < 4; ++mi)
#pragma unroll
      for (int ni = 0; ni < 4; ++ni)
        acc[mi][ni] = __builtin_amdgcn_mfma_f32_16x16x32_bf16(af[mi], bfr[ni], acc[mi][ni], 0, 0, 0);
  }

  const int rowbase = tileM + wm * 64 + ((lane >> 4) << 2);
  const int colbase = tileN + wn * 64 + (lane & 15);
#pragma unroll
  for (int ni = 0; ni < 4; ++ni) {
    const int col = colbase + ni * 16;
    float bv = 0.f;
    if constexpr (HAS_BIAS) bv = bias[col];
#pragma unroll
    for (int mi = 0; mi < 4; ++mi) {
#pragma unroll
      for (int r = 0; r < 4; ++r) {
        const int row = rowbase + mi * 16 + r;
        float v = acc[mi][ni][r] + bv;
        if constexpr (EXP_OUT) v = __expf(v);
        const long idx = (long)bz * sC + (long)row * N + col;
        if constexpr (OUT_F32) ((float*)C)[idx] = v;
        else ((ushort*)C)[idx] = f2bf(v);
      }
    }
  }
}

// ================= 256-row-tile deep-pipelined GEMM core =================
// C[m,n] = sum_k A[m,k]*B[n,k].  K = 1024 fixed (32 K-tiles of 32).
// 512 threads / 8 waves, BM=256, NB in {128,256}.  4-deep LDS ring,
// counted vmcnt (2 K-tiles of loads stay in flight across raw s_barriers),
// XOR-swizzled LDS realized via pre-swizzled global source addresses
// (linear global_load_lds dest), setprio around MFMA clusters,
// bijective XCD-chunked block remap (all grids are exactly 256 blocks).
// MODE: 0 = dual bf16 out (C1 cols<1024 w/ bias1, C2 w/ bias2)
//       1 = bf16 out, bias + exp
//       2 = bf16 out, split-K partial layout  C1 + ((z&1)*4 + z>>1)*NW
//       3 = f32 out, z-batched by sCz
template<int NB, int MODE>
__global__ __launch_bounds__(512, 2)
void gemm8(const ushort* __restrict__ A, const ushort* __restrict__ Bm,
           const float* __restrict__ bias1, const float* __restrict__ bias2,
           void* __restrict__ C1, void* __restrict__ C2,
           int ldA, int ldB, long sAz, long sBz, long sCz)
{
  constexpr int LPT = 2 + NB / 128;      // global_load_lds insts per K-tile
  constexpr int WN  = NB / 64;           // waves along N
  constexpr int WM  = 8 / WN;            // waves along M
  constexpr int MR  = 256 / (16 * WM);   // M fragments per wave (8 or 4)
  constexpr int MW  = 256 / WM;          // per-wave M span
  constexpr int MH  = MR / 2;

  __shared__ alignas(16) ushort Ab[4][256 * 32];
  __shared__ alignas(16) ushort Bb[4][NB * 32];

  // bijective XCD-chunked remap (nwg == 256, 256 % 8 == 0)
  const int gx = gridDim.x, gy = gridDim.y;
  const int nwg = gx * gy * gridDim.z;
  int fid = (blockIdx.z * gy + blockIdx.y) * gx + blockIdx.x;
  fid = (fid & 7) * (nwg >> 3) + (fid >> 3);
  const int bx = fid % gx;
  const int by = (fid / gx) % gy;
  const int bz = fid / (gx * gy);

  const int tileM = by * 256, tileN = bx * NB;

  const ushort* Ap = A;
  const ushort* Bp = Bm;
  if constexpr (MODE == 2) {
    Ap += (long)(bz >> 1) * sAz + (long)(bz & 1) * 1024;
    Bp += (long)(bz >> 1) * sBz + (long)(bz & 1) * 1024;
  } else {
    Ap += (long)bz * sAz;
    Bp += (long)bz * sBz;
  }

  const int tid  = threadIdx.x;
  const int wid  = tid >> 6;
  const int lane = tid & 63;
  const int wm   = wid / WN;
  const int wn   = wid % WN;

  // staging: thread tid fills LDS elems [inst*4096 + tid*8, +8)
  //   row r = inst*128 + (tid>>2); swizzled col c' = (tid&3)*8
  //   global col = c' ^ swz(r), swz(r) = ((r>>1)&3)*8  (inst-invariant)
  const int srow = tid >> 2;
  const int scol = (((tid & 3) ^ ((tid >> 3) & 3)) << 3);
  const ushort* gA0 = Ap + (long)(tileM + srow) * ldA + scol;
  const ushort* gA1 = Ap + (long)(tileM + 128 + srow) * ldA + scol;
  const ushort* gB0 = Bp + (long)(tileN + srow) * ldB + scol;
  const ushort* gB1 = (NB == 256) ? (Bp + (long)(tileN + 128 + srow) * ldB + scol) : gB0;
  const int wofs = wid << 9;             // wave LDS base (elems)

  // fragment reads: row fr = base + frow, col = kg*8 ^ swz(fr) -> uniform per bank
  const int frow  = lane & 15;
  const int cofs  = (((lane >> 4) ^ ((lane >> 1) & 3)) << 3);
  const int abase = wm * MW + frow;
  const int bbase = wn * 64 + frow;

  f32x4 acc[MR][4];
#pragma unroll
  for (int i = 0; i < MR; ++i)
#pragma unroll
    for (int j = 0; j < 4; ++j) acc[i][j] = (f32x4){0.f, 0.f, 0.f, 0.f};

  // prologue: stage K-tiles 0,1,2 into ring slots 0,1,2
#pragma unroll
  for (int p = 0; p < 3; ++p) {
    const int kt = p * 32;
    async16(gA0 + kt, Ab[p] + wofs);
    async16(gA1 + kt, Ab[p] + 4096 + wofs);
    async16(gB0 + kt, Bb[p] + wofs);
    if constexpr (NB == 256) async16(gB1 + kt, Bb[p] + 4096 + wofs);
  }
  if constexpr (LPT == 4) asm volatile("s_waitcnt vmcnt(8)" ::: "memory");
  else                    asm volatile("s_waitcnt vmcnt(6)" ::: "memory");
  __builtin_amdgcn_s_barrier();

  for (int t = 0; t < 32; ++t) {
    const int cur = t & 3;
    const int nxt = (t + 3) & 3;
    const int kt3 = (t + 3) * 32;
    const bool st = (t < 29);
    const ushort* __restrict__ Ac = Ab[cur];
    const ushort* __restrict__ Bc = Bb[cur];

    // ---- sub-phase 0: B frags + first half of A frags; stage 2 insts
    bf16x8 bf[4], af[MH];
#pragma unroll
    for (int ni = 0; ni < 4; ++ni)
      bf[ni] = *(const bf16x8*)(Bc + (bbase + ni * 16) * 32 + cofs);
#pragma unroll
    for (int mi = 0; mi < MH; ++mi)
      af[mi] = *(const bf16x8*)(Ac + (abase + mi * 16) * 32 + cofs);
    if (st) {
      async16(gA0 + kt3, Ab[nxt] + wofs);
      async16(gB0 + kt3, Bb[nxt] + wofs);
    }
    __builtin_amdgcn_s_barrier();
    __builtin_amdgcn_s_setprio(1);
#pragma unroll
    for (int mi = 0; mi < MH; ++mi)
#pragma unroll
      for (int ni = 0; ni < 4; ++ni)
        acc[mi][ni] = __builtin_amdgcn_mfma_f32_16x16x32_bf16(af[mi], bf[ni], acc[mi][ni], 0, 0, 0);
    __builtin_amdgcn_s_setprio(0);
    __builtin_amdgcn_s_barrier();

    // ---- sub-phase 1: second half of A frags (B reused); stage rest
    bf16x8 ag[MH];
#pragma unroll
    for (int mi = 0; mi < MH; ++mi)
      ag[mi] = *(const bf16x8*)(Ac + (abase + (MH + mi) * 16) * 32 + cofs);
    if (st) {
      async16(gA1 + kt3, Ab[nxt] + 4096 + wofs);
      if constexpr (NB == 256) async16(gB1 + kt3, Bb[nxt] + 4096 + wofs);
    }
    __builtin_amdgcn_s_barrier();
    __builtin_amdgcn_s_setprio(1);
#pragma unroll
    for (int mi = 0; mi < MH; ++mi)
#pragma unroll
      for (int ni = 0; ni < 4; ++ni)
        acc[MH + mi][ni] = __builtin_amdgcn_mfma_f32_16x16x32_bf16(ag[mi], bf[ni], acc[MH + mi][ni], 0, 0, 0);
    __builtin_amdgcn_s_setprio(0);
    // once per K-tile: counted drain so tile t+1 is resident; t+2,t+3 stay in flight
    if (t < 29) {
      if constexpr (LPT == 4) asm volatile("s_waitcnt vmcnt(8)" ::: "memory");
      else                    asm volatile("s_waitcnt vmcnt(6)" ::: "memory");
    } else if (t == 29) {
      if constexpr (LPT == 4) asm volatile("s_waitcnt vmcnt(4)" ::: "memory");
      else                    asm volatile("s_waitcnt vmcnt(3)" ::: "memory");
    } else if (t == 30) {
      asm volatile("s_waitcnt vmcnt(0)" ::: "memory");
    }
    __builtin_amdgcn_s_barrier();
  }

  // ---- epilogue
  const int rowbase  = tileM + wm * MW + ((lane >> 4) << 2);
  const int colbase0 = wn * 64 + (lane & 15);

  if constexpr (MODE == 0) {
    const bool second = tileN >= 1024;
    ushort* Cp = (ushort*)(second ? C2 : C1);
    const float* bb = second ? bias2 : bias1;
    const int cb = tileN - (second ? 1024 : 0) + colbase0;
#pragma unroll
    for (int ni = 0; ni < 4; ++ni) {
      const int col = cb + ni * 16;
      const float bv = bb[col];
#pragma unroll
      for (int mi = 0; mi < MR; ++mi)
#pragma unroll
        for (int r = 0; r < 4; ++r)
          Cp[(long)(rowbase + mi * 16 + r) * 1024 + col] = f2bf(acc[mi][ni][r] + bv);
    }
  } else if constexpr (MODE == 1) {
    ushort* Cp = (ushort*)C1;
    const int cb = tileN + colbase0;
#pragma unroll
    for (int ni = 0; ni < 4; ++ni) {
      const int col = cb + ni * 16;
      const float bv = bias1[col];
#pragma unroll
      for (int mi = 0; mi < MR; ++mi)
#pragma unroll
        for (int r = 0; r < 4; ++r)
          Cp[(long)(rowbase + mi * 16 + r) * 1024 + col] = f2bf(__expf(acc[mi][ni][r] + bv));
    }
  } else if constexpr (MODE == 2) {
    ushort* Cp = (ushort*)C1 + ((long)(bz & 1) * B_ + (bz >> 1)) * ((long)D_ * D_);
    const int cb = tileN + colbase0;
#pragma unroll
    for (int ni = 0; ni < 4; ++ni) {
      const int col = cb + ni * 16;
#pragma unroll
      for (int mi = 0; mi < MR; ++mi)
#pragma unroll
        for (int r = 0; r < 4; ++r)
          Cp[(long)(rowbase + mi * 16 + r) * 1024 + col] = f2bf(acc[mi][ni][r]);
    }
  } else {
    float* Cp = (float*)C1 + (long)bz * sCz;
    const int cb = tileN + colbase0;
#pragma unroll
    for (int ni = 0; ni < 4; ++ni) {
      const int col = cb + ni * 16;
#pragma unroll
      for (int mi = 0; mi < MR; ++mi)
#pragma unroll
        for (int r = 0; r < 4; ++r)
          Cp[(long)(rowbase + mi * 16 + r) * 1024 + col] = acc[mi][ni][r];
    }
  }
}

// MT2[b][d][e] = (p0+p1) * cinv[b][e] ; 8 elems/thread over B_*NW.
__global__ __launch_bounds__(256)
void reduce2_scale(const ushort* __restrict__ P, const float* __restrict__ cinv,
                   ushort* __restrict__ MT)
{
  const long stride = (long)B_ * D_ * D_;
  const long base = ((long)blockIdx.x * 256 + threadIdx.x) * 8;
  const int b = (int)(base >> 20);            // NW = 2^20
  const int e0 = (int)(base & (D_ - 1));
  bf16x8 p0 = *(const bf16x8*)(P + base);
  bf16x8 p1 = *(const bf16x8*)(P + stride + base);
  const float4 c0 = *(const float4*)(cinv + (long)b * D_ + e0);
  const float4 c1 = *(const float4*)(cinv + (long)b * D_ + e0 + 4);
  const float cc[8] = {c0.x, c0.y, c0.z, c0.w, c1.x, c1.y, c1.z, c1.w};
  bf16x8 o;
#pragma unroll
  for (int j = 0; j < 8; ++j)
    o[j] = (short)f2bf((bf2f((ushort)p0[j]) + bf2f((ushort)p1[j])) * cc[j]);
  *(bf16x8*)(MT + base) = o;
}

// row softmax, no max subtraction (|logits| bounded ~3). bf16 in/out in place.
__global__ __launch_bounds__(256)
void softmax_row(ushort* __restrict__ S)
{
  const long base = (long)blockIdx.x * D_;
  const int tid = threadIdx.x;
  float e[4], s = 0.f;
#pragma unroll
  for (int i = 0; i < 4; ++i) { e[i] = __expf(bf2f(S[base + i * 256 + tid])); s += e[i]; }
#pragma unroll
  for (int off = 32; off; off >>= 1) s += __shfl_xor(s, off);
  __shared__ float reds[4];
  if ((tid & 63) == 0) reds[tid >> 6] = s;
  __syncthreads();
  s = reds[0] + reds[1] + reds[2] + reds[3];
  const float inv = 1.f / s;
#pragma unroll
  for (int i = 0; i < 4; ++i)
    S[base + i * 256 + tid] = f2bf(e[i] * inv);
}

// merged transpose of l and ov: z in [0,B_): bufB->xBf ; [B_,2B_): bufA->scr. [T][D]->[D][T]
__global__ __launch_bounds__(256)
void transpose2(const ushort* __restrict__ l, ushort* __restrict__ lT,
                const ushort* __restrict__ ov, ushort* __restrict__ ovT)
{
  __shared__ alignas(16) ushort t[64 * 65];
  const int z = blockIdx.z;
  const int b = z & (B_ - 1);
  const ushort* in = (z < B_ ? l : ov) + (long)b * T_ * D_;
  ushort* out      = (z < B_ ? lT : ovT) + (long)b * (long)D_ * T_;
  const int c0 = blockIdx.x * 64, r0 = blockIdx.y * 64;
  const int tx = threadIdx.x & 15, ty = threadIdx.x >> 4;
#pragma unroll
  for (int i = 0; i < 4; ++i) {
    const int r = ty + i * 16;
    u16x4 v = *(const u16x4*)(in + (long)(r0 + r) * D_ + c0 + tx * 4);
#pragma unroll
    for (int c = 0; c < 4; ++c) t[(tx * 4 + c) * 65 + r] = v[c];
  }
  __syncthreads();
#pragma unroll
  for (int i = 0; i < 4; ++i) {
    const int c = ty + i * 16;
    u16x4 v;
#pragma unroll
    for (int j = 0; j < 4; ++j) v[j] = t[c * 65 + tx * 4 + j];
    *(u16x4*)(out + (long)(c0 + c) * T_ + r0 + tx * 4) = v;
  }
}

// column sums of E over T_ rows, chunked. grid (D_/256, 16, B_).
__global__ __launch_bounds__(256)
void colsum_part(const ushort* __restrict__ E, float* __restrict__ psum)
{
  const int d = blockIdx.x * 256 + threadIdx.x;
  const int c = blockIdx.y;
  const int b = blockIdx.z;
  const ushort* p = E + ((long)b * T_ + (long)c * 128) * D_ + d;
  float s = 0.f;
#pragma unroll 4
  for (int r = 0; r < 128; ++r) s += bf2f(p[(long)r * D_]);
  psum[((long)b * 16 + c) * D_ + d] = s;
}

// cinv = 1/sum over chunks. grid (D_/256, B_).
__global__ __launch_bounds__(256)
void colsum_comb(const float* __restrict__ psum, float* __restrict__ cinv)
{
  const int d = blockIdx.x * 256 + threadIdx.x;
  const int b = blockIdx.y;
  float s = 0.f;
#pragma unroll
  for (int c = 0; c < 16; ++c) s += psum[((long)b * 16 + c) * D_ + d];
  cinv[(long)b * D_ + d] = 1.f / s;
}

extern "C" void kernel_launch(void* const* d_in, const int* in_sizes, int n_in,
                              void* d_out, int out_size, void* d_ws, size_t ws_size,
                              hipStream_t stream)
{
  (void)in_sizes; (void)n_in; (void)out_size; (void)ws_size;
  const float* lat = (const float*)d_in[0];
  const float* inp = (const float*)d_in[1];
  const float* Wl  = (const float*)d_in[2];
  const float* bl  = (const float*)d_in[3];
  const float* Wu  = (const float*)d_in[4];
  const float* bu  = (const float*)d_in[5];
  const float* WA  = (const float*)d_in[6];
  const float* bA  = (const float*)d_in[7];
  const float* WV  = (const float*)d_in[8];
  const float* bV  = (const float*)d_in[9];
  const float* Wo  = (const float*)d_in[10];
  const float* bo  = (const float*)d_in[11];

  char* w = (char*)d_ws;
  auto carve = [&](size_t bytes) { char* p = w; w += (bytes + 255) & ~(size_t)255; return p; };
  const long NT = (long)B_ * T_ * D_;
  const long NW = (long)D_ * D_;
  ushort* xBf   = (ushort*)carve(NT * 2);
  ushort* xBf2  = (ushort*)carve(NT * 2);
  ushort* bufA  = (ushort*)carve(NT * 2);
  ushort* bufB  = (ushort*)carve(NT * 2);
  ushort* scr   = (ushort*)carve(NT * 2);
  ushort* MT    = (ushort*)carve((long)B_ * NW * 2);
  ushort* wCat  = (ushort*)carve(3 * NW * 2);
  float*  bc    = (float*)carve(D_ * 4);
  float*  bc2   = (float*)carve(D_ * 4);
  float*  psum  = (float*)carve(64 * 1024 * 4);
  float*  cinv  = (float*)carve(8 * 1024 * 4);
  ushort* w1 = scr;            // [Wu_bf ; WV_bf]
  ushort* w2 = scr + 2 * NW;   // [WlT ; WAT]
  ushort* ovT = scr;           // after weight-compose, scr is dead -> ovT
  ushort* part = bufB;         // after l transposed out, bufB is dead -> splitk partials

  const dim3 blk(256, 1, 1);
  const dim3 blk5(512, 1, 1);

  // 1. fused prep
  prep<<<dim3(20480), blk, 0, stream>>>(lat, inp, Wl, bl, Wu, bu, WA, bA, WV, bV, Wo, bo,
                                        xBf, xBf2, w1, w2, wCat + NW, bc, bc2);
  // 2. weight compose: z0: Wc=Wu·Wl -> wCat[0]; z1: Wc2=WV·WA -> wCat[2NW]
  gemm_nt<false, false, false><<<dim3(8, 8, 2), blk, 0, stream>>>(
      w1, w2, nullptr, wCat, D_, D_, NW, NW, 2 * NW);
  // 3. S1 (bufB) + ov (bufA) in one N=2048 GEMM over [Wc ; Wo]  (256-tile core)
  gemm8<256, 0><<<dim3(8, 32, 1), blk5, 0, stream>>>(
      xBf, wCat, bc, bo, bufB, bufA, D_, D_, 0, 0, 0);
  // 4. l = row-softmax(S1), in place
  softmax_row<<<dim3(B_ * T_), blk, 0, stream>>>(bufB);
  // 5. lT (bufB->xBf) + ovT (bufA->scr), one launch
  transpose2<<<dim3(16, 32, 2 * B_), blk, 0, stream>>>(bufB, xBf, bufA, ovT);
  // 6. MT partials: MT[d,e] = sum_q ovT[d,q]·lT[e,q], split-K=2 -> bufB
  gemm8<128, 2><<<dim3(8, 4, 8), blk5, 0, stream>>>(
      ovT, xBf, nullptr, nullptr, part, nullptr, T_, T_, (long)D_ * T_, (long)D_ * T_, 0);
  // 7. E = exp(inp @ Wc2^T + bc2) -> bufA
  gemm8<128, 1><<<dim3(8, 32, 1), blk5, 0, stream>>>(
      xBf2, wCat + 2 * NW, bc2, nullptr, bufA, nullptr, D_, D_, 0, 0, 0);
  // 8-9. column sums of E -> cinv
  colsum_part<<<dim3(4, 16, B_), blk, 0, stream>>>(bufA, psum);
  colsum_comb<<<dim3(4, B_, 1), blk, 0, stream>>>(psum, cinv);
  // 10. MT2 = (partial sum) * cinv[e]
  reduce2_scale<<<dim3(2048), blk, 0, stream>>>(part, cinv, MT);
  // 11. o = E @ MT2^T -> d_out (fp32)
  gemm8<128, 3><<<dim3(8, 8, 4), blk5, 0, stream>>>(
      bufA, MT, nullptr, nullptr, d_out, nullptr, D_, D_,
      (long)T_ * D_, NW, (long)T_ * D_);
}